// Round 1
// baseline (14293.674 us; speedup 1.0000x reference)
//
#include <hip/hip_runtime.h>
#include <cstdint>

typedef unsigned short u16;
typedef unsigned int u32;
typedef __bf16 bf16_t;
typedef bf16_t bf16x8 __attribute__((ext_vector_type(8)));
typedef float f32x4 __attribute__((ext_vector_type(4)));

#define DMODEL 4096
#define DFF 11008
#define MROWS 8192

__device__ __forceinline__ u16 f2bf(float f) {
  u32 u = __builtin_bit_cast(u32, f);
  u += 0x7FFFu + ((u >> 16) & 1u);   // RNE
  return (u16)(u >> 16);
}
__device__ __forceinline__ float bf2f(u16 h) {
  return __builtin_bit_cast(float, (u32)h << 16);
}

// ---------------- x -> bf16 ----------------
__global__ void k_cvt_x(const float* __restrict__ x, u16* __restrict__ xb) {
  size_t i = (size_t)blockIdx.x * blockDim.x + threadIdx.x;
  float4 v = reinterpret_cast<const float4*>(x)[i];
  ushort4 o;
  o.x = f2bf(v.x); o.y = f2bf(v.y); o.z = f2bf(v.z); o.w = f2bf(v.w);
  reinterpret_cast<ushort4*>(xb)[i] = o;
}

// ------- dequant (q - z) * s, write TRANSPOSED wT[N][K] as bf16 -------
// q[K][N] int32 (4-bit values), z[K/128][N] int32, s[K/128][N] f32
__global__ void k_dequant_T(const int* __restrict__ q, const int* __restrict__ z,
                            const float* __restrict__ s, u16* __restrict__ wT,
                            int K, int N) {
  __shared__ u16 tile[32][33];  // +1 pad breaks transpose bank conflicts
  const int tx = threadIdx.x & 31, ty = threadIdx.x >> 5;
  const int n0 = blockIdx.x << 5, k0 = blockIdx.y << 5;
#pragma unroll
  for (int i = 0; i < 4; ++i) {
    int r = ty + i * 8;
    int k = k0 + r;
    int g = k >> 7;  // group = k / 128
    size_t zoff = (size_t)g * N + n0 + tx;
    float val = (float)(q[(size_t)k * N + n0 + tx] - z[zoff]) * s[zoff];
    tile[r][tx] = f2bf(val);
  }
  __syncthreads();
#pragma unroll
  for (int i = 0; i < 4; ++i) {
    int r = ty + i * 8;
    wT[(size_t)(n0 + r) * K + k0 + tx] = tile[tx][r];
  }
}

// ---------------- GEMM: C[M,N] = A[M,K] * BT[N,K]^T (bf16 in, f32 acc) -----
// EPI 0: C=bf16 store (gate)
// EPI 1: C bf16 buffer holding gate; C[idx] = silu(C[idx]) * acc  (h, in place)
// EPI 2: C=f32 store (final out)
template <int EPI>
__global__ __launch_bounds__(256, 2) void k_gemm(
    const u16* __restrict__ A, const u16* __restrict__ BT,
    void* C, int Mdim, int Ndim, int Kdim) {
  constexpr int BK = 64;
  __shared__ u16 As[128 * BK];
  __shared__ u16 Bs[128 * BK];

  const int nbn = Ndim / 128;
  const int m0 = (blockIdx.x / nbn) * 128;
  const int n0 = (blockIdx.x % nbn) * 128;
  const int t = threadIdx.x;
  const int lane = t & 63;
  const int wid = t >> 6;
  const int wr = wid >> 1, wc = wid & 1;     // 2x2 waves, 64x64 each
  const int r16 = lane & 15, quad = lane >> 4;

  // staging decomposition: 16B chunks; thread covers (row = i*32 + t/8, slot = t&7)
  const int srow = t >> 3;
  const int sslot = t & 7;
  const u16* Ab = A + (size_t)m0 * Kdim + sslot * 8;
  const u16* Bb = BT + (size_t)n0 * Kdim + sslot * 8;

  uint4 ra[4], rb[4];
  auto stage_load = [&](int k0) {
#pragma unroll
    for (int i = 0; i < 4; ++i) {
      int row = i * 32 + srow;
      ra[i] = *reinterpret_cast<const uint4*>(Ab + (size_t)row * Kdim + k0);
      rb[i] = *reinterpret_cast<const uint4*>(Bb + (size_t)row * Kdim + k0);
    }
  };
  auto stage_write = [&]() {
#pragma unroll
    for (int i = 0; i < 4; ++i) {
      int row = i * 32 + srow;
      int ws_ = sslot ^ (row & 7);  // XOR swizzle: kills 8-way read conflicts
      *reinterpret_cast<uint4*>(&As[row * 64 + ws_ * 8]) = ra[i];
      *reinterpret_cast<uint4*>(&Bs[row * 64 + ws_ * 8]) = rb[i];
    }
  };

  f32x4 acc[4][4];
  const f32x4 zf = {0.f, 0.f, 0.f, 0.f};
#pragma unroll
  for (int mi = 0; mi < 4; ++mi)
#pragma unroll
    for (int ni = 0; ni < 4; ++ni) acc[mi][ni] = zf;

  const int nk = Kdim / BK;
  stage_load(0);
  for (int kt = 0; kt < nk; ++kt) {
    stage_write();
    __syncthreads();
    if (kt + 1 < nk) stage_load((kt + 1) * BK);  // in flight across the MFMAs
#pragma unroll
    for (int kk = 0; kk < 2; ++kk) {
      bf16x8 av[4], bv[4];
#pragma unroll
      for (int mi = 0; mi < 4; ++mi) {
        int row = wr * 64 + mi * 16 + r16;
        int sl = (kk * 4 + quad) ^ (row & 7);
        av[mi] = *reinterpret_cast<const bf16x8*>(&As[row * 64 + sl * 8]);
      }
#pragma unroll
      for (int ni = 0; ni < 4; ++ni) {
        int row = wc * 64 + ni * 16 + r16;
        int sl = (kk * 4 + quad) ^ (row & 7);
        bv[ni] = *reinterpret_cast<const bf16x8*>(&Bs[row * 64 + sl * 8]);
      }
#pragma unroll
      for (int mi = 0; mi < 4; ++mi)
#pragma unroll
        for (int ni = 0; ni < 4; ++ni)
          acc[mi][ni] = __builtin_amdgcn_mfma_f32_16x16x32_bf16(
              av[mi], bv[ni], acc[mi][ni], 0, 0, 0);
    }
    __syncthreads();
  }

  // C/D layout (m89-verified): col = lane&15, row = quad*4 + j
  const int rb0 = m0 + wr * 64 + quad * 4;
  const int cb0 = n0 + wc * 64 + r16;
#pragma unroll
  for (int mi = 0; mi < 4; ++mi) {
#pragma unroll
    for (int ni = 0; ni < 4; ++ni) {
      f32x4 v = acc[mi][ni];
      int col = cb0 + ni * 16;
      int row = rb0 + mi * 16;
#pragma unroll
      for (int j = 0; j < 4; ++j) {
        size_t idx = (size_t)(row + j) * Ndim + col;
        if constexpr (EPI == 0) {
          ((u16*)C)[idx] = f2bf(v[j]);
        } else if constexpr (EPI == 1) {
          u16* Cp = (u16*)C;
          float g = bf2f(Cp[idx]);
          float sv = g / (1.f + __expf(-g));  // silu(gate)
          Cp[idx] = f2bf(sv * v[j]);          // h = silu(gate)*up, in place
        } else {
          ((float*)C)[idx] = v[j];
        }
      }
    }
  }
}

extern "C" void kernel_launch(void* const* d_in, const int* in_sizes, int n_in,
                              void* d_out, int out_size, void* d_ws, size_t ws_size,
                              hipStream_t stream) {
  const float* x  = (const float*)d_in[0];
  const int*   qg = (const int*)d_in[1];
  const int*   zg = (const int*)d_in[2];
  const float* sg = (const float*)d_in[3];
  const int*   qu = (const int*)d_in[4];
  const int*   zu = (const int*)d_in[5];
  const float* su = (const float*)d_in[6];
  const int*   qd = (const int*)d_in[7];
  const int*   zd = (const int*)d_in[8];
  const float* sd = (const float*)d_in[9];
  float* out = (float*)d_out;

  // workspace layout (518 MB total)
  char* ws = (char*)d_ws;
  const size_t szXB = (size_t)MROWS * DMODEL * 2;  // 67,108,864
  const size_t szW  = (size_t)DMODEL * DFF * 2;    // 90,177,536
  u16* xb   = (u16*)(ws);
  u16* wgT  = (u16*)(ws + szXB);
  u16* wuT  = (u16*)(ws + szXB + szW);
  u16* wdT  = (u16*)(ws + szXB + 2 * szW);
  u16* gate = (u16*)(ws + szXB + 3 * szW);         // [M][DFF] bf16; becomes h in place

  k_cvt_x<<<(MROWS * DMODEL) / 1024, 256, 0, stream>>>(x, xb);
  k_dequant_T<<<dim3(DFF / 32, DMODEL / 32), 256, 0, stream>>>(qg, zg, sg, wgT, DMODEL, DFF);
  k_dequant_T<<<dim3(DFF / 32, DMODEL / 32), 256, 0, stream>>>(qu, zu, su, wuT, DMODEL, DFF);
  k_dequant_T<<<dim3(DMODEL / 32, DFF / 32), 256, 0, stream>>>(qd, zd, sd, wdT, DFF, DMODEL);

  // gate = x @ Wg  (bf16 out)
  k_gemm<0><<<(MROWS / 128) * (DFF / 128), 256, 0, stream>>>(xb, wgT, gate, MROWS, DFF, DMODEL);
  // h = silu(gate) * (x @ Wu)  (in place over gate)
  k_gemm<1><<<(MROWS / 128) * (DFF / 128), 256, 0, stream>>>(xb, wuT, gate, MROWS, DFF, DMODEL);
  // out = h @ Wd  (f32 out)
  k_gemm<2><<<(MROWS / 128) * (DMODEL / 128), 256, 0, stream>>>(gate, wdT, out, MROWS, DMODEL, DFF);
}

// Round 2
// 2935.383 us; speedup vs baseline: 4.8694x; 4.8694x over previous
//
#include <hip/hip_runtime.h>
#include <cstdint>

typedef unsigned short u16;
typedef unsigned int u32;
typedef __bf16 bf16_t;
typedef bf16_t bf16x8 __attribute__((ext_vector_type(8)));
typedef float f32x4 __attribute__((ext_vector_type(4)));

#define DMODEL 4096
#define DFF 11008
#define MROWS 8192

__device__ __forceinline__ u16 f2bf(float f) {
  u32 u = __builtin_bit_cast(u32, f);
  u += 0x7FFFu + ((u >> 16) & 1u);   // RNE
  return (u16)(u >> 16);
}
__device__ __forceinline__ float bf2f(u16 h) {
  return __builtin_bit_cast(float, (u32)h << 16);
}

// async global->LDS, 16B per lane, wave-uniform LDS base + lane*16
#define GLD16(gptr, lptr)                                                  \
  __builtin_amdgcn_global_load_lds(                                        \
      (const __attribute__((address_space(1))) u32*)(gptr),                \
      (__attribute__((address_space(3))) u32*)(lptr), 16, 0, 0)

// ---------------- x -> bf16 ----------------
__global__ void k_cvt_x(const float* __restrict__ x, u16* __restrict__ xb) {
  size_t i = (size_t)blockIdx.x * blockDim.x + threadIdx.x;
  float4 v = reinterpret_cast<const float4*>(x)[i];
  ushort4 o;
  o.x = f2bf(v.x); o.y = f2bf(v.y); o.z = f2bf(v.z); o.w = f2bf(v.w);
  reinterpret_cast<ushort4*>(xb)[i] = o;
}

// ------- dequant (q - z) * s, write TRANSPOSED wT[N][K] as bf16 -------
__global__ void k_dequant_T(const int* __restrict__ q, const int* __restrict__ z,
                            const float* __restrict__ s, u16* __restrict__ wT,
                            int K, int N) {
  __shared__ u16 tile[32][33];
  const int tx = threadIdx.x & 31, ty = threadIdx.x >> 5;
  const int n0 = blockIdx.x << 5, k0 = blockIdx.y << 5;
#pragma unroll
  for (int i = 0; i < 4; ++i) {
    int r = ty + i * 8;
    int k = k0 + r;
    int g = k >> 7;
    size_t zoff = (size_t)g * N + n0 + tx;
    float val = (float)(q[(size_t)k * N + n0 + tx] - z[zoff]) * s[zoff];
    tile[r][tx] = f2bf(val);
  }
  __syncthreads();
#pragma unroll
  for (int i = 0; i < 4; ++i) {
    int r = ty + i * 8;
    wT[(size_t)(n0 + r) * K + k0 + tx] = tile[tx][r];
  }
}

// ---------------- GEMM: C[M,N] = A[M,K] * BT[N,K]^T (bf16 in, f32 acc) -----
// EPI 0: C=bf16 store (gate)
// EPI 1: C bf16 holds gate; C = silu(C) * acc  (h, in place)
// EPI 2: C=f32 store (final out)
template <int EPI>
__global__ __launch_bounds__(256) void k_gemm(
    const u16* __restrict__ A, const u16* __restrict__ BT,
    void* C, int Mdim, int Ndim, int Kdim) {
  constexpr int BK = 64;
  __shared__ u16 As[128 * BK];  // linear [row][64], XOR-swizzled contents
  __shared__ u16 Bs[128 * BK];

  const int nbn = Ndim / 128;
  int bid = blockIdx.x;
  {  // XCD-aware swizzle (grid % 8 == 0 for all three GEMMs here)
    const int cpx = gridDim.x >> 3;
    bid = (bid & 7) * cpx + (bid >> 3);
  }
  const int m0 = (bid / nbn) * 128;
  const int n0 = (bid % nbn) * 128;
  const int t = threadIdx.x;
  const int lane = t & 63;
  const int wid = t >> 6;
  const int wr = wid >> 1, wc = wid & 1;  // 2x2 waves, 64x64 each
  const int r16 = lane & 15, quad = lane >> 4;

  // Staging: wave `wid` fills rows [wid*32, wid*32+32) of As and Bs with 4
  // GLD16 each (one instr = 64 lanes x 16B = 8 rows). Lane l lands at LDS
  // (row = r0 + l/8, slot = l&7); we want LDS[row][s] = G[row][s ^ (row&7)],
  // so the SOURCE slot is (l&7) ^ (l>>3)  (r0 is a multiple of 8).
  const int lrow8 = lane >> 3;
  const int gslot = (lane & 7) ^ lrow8;
  const u16* Abase = A + (size_t)(m0 + wid * 32 + lrow8) * Kdim + gslot * 8;
  const u16* Bbase = BT + (size_t)(n0 + wid * 32 + lrow8) * Kdim + gslot * 8;

  f32x4 acc[4][4];
  const f32x4 zf = {0.f, 0.f, 0.f, 0.f};
#pragma unroll
  for (int mi = 0; mi < 4; ++mi)
#pragma unroll
    for (int ni = 0; ni < 4; ++ni) acc[mi][ni] = zf;

  const int nk = Kdim / BK;
  for (int kt = 0; kt < nk; ++kt) {
    const int k0 = kt * BK;
    __syncthreads();  // previous iter's LDS reads complete
#pragma unroll
    for (int i = 0; i < 4; ++i) {
      GLD16(Abase + (size_t)(i * 8) * Kdim + k0, &As[(wid * 32 + i * 8) * 64]);
      GLD16(Bbase + (size_t)(i * 8) * Kdim + k0, &Bs[(wid * 32 + i * 8) * 64]);
    }
    __syncthreads();  // compiler drains vmcnt(0) before barrier -> LDS valid
#pragma unroll
    for (int kk = 0; kk < 2; ++kk) {
      bf16x8 av[4], bv[4];
#pragma unroll
      for (int mi = 0; mi < 4; ++mi) {
        int row = wr * 64 + mi * 16 + r16;
        int sl = (kk * 4 + quad) ^ (row & 7);
        av[mi] = *reinterpret_cast<const bf16x8*>(&As[row * 64 + sl * 8]);
      }
#pragma unroll
      for (int ni = 0; ni < 4; ++ni) {
        int row = wc * 64 + ni * 16 + r16;
        int sl = (kk * 4 + quad) ^ (row & 7);
        bv[ni] = *reinterpret_cast<const bf16x8*>(&Bs[row * 64 + sl * 8]);
      }
#pragma unroll
      for (int mi = 0; mi < 4; ++mi)
#pragma unroll
        for (int ni = 0; ni < 4; ++ni)
          acc[mi][ni] = __builtin_amdgcn_mfma_f32_16x16x32_bf16(
              av[mi], bv[ni], acc[mi][ni], 0, 0, 0);
    }
  }

  // C/D layout: col = lane&15, row = quad*4 + j  (m89-verified)
  const int rb0 = m0 + wr * 64 + quad * 4;
  const int cb0 = n0 + wc * 64 + r16;
#pragma unroll
  for (int mi = 0; mi < 4; ++mi) {
#pragma unroll
    for (int ni = 0; ni < 4; ++ni) {
      f32x4 v = acc[mi][ni];
      int col = cb0 + ni * 16;
      int row = rb0 + mi * 16;
#pragma unroll
      for (int j = 0; j < 4; ++j) {
        size_t idx = (size_t)(row + j) * Ndim + col;
        if constexpr (EPI == 0) {
          ((u16*)C)[idx] = f2bf(v[j]);
        } else if constexpr (EPI == 1) {
          u16* Cp = (u16*)C;
          float g = bf2f(Cp[idx]);
          float sv = g / (1.f + __expf(-g));
          Cp[idx] = f2bf(sv * v[j]);
        } else {
          ((float*)C)[idx] = v[j];
        }
      }
    }
  }
}

extern "C" void kernel_launch(void* const* d_in, const int* in_sizes, int n_in,
                              void* d_out, int out_size, void* d_ws, size_t ws_size,
                              hipStream_t stream) {
  const float* x  = (const float*)d_in[0];
  const int*   qg = (const int*)d_in[1];
  const int*   zg = (const int*)d_in[2];
  const float* sg = (const float*)d_in[3];
  const int*   qu = (const int*)d_in[4];
  const int*   zu = (const int*)d_in[5];
  const float* su = (const float*)d_in[6];
  const int*   qd = (const int*)d_in[7];
  const int*   zd = (const int*)d_in[8];
  const float* sd = (const float*)d_in[9];
  float* out = (float*)d_out;

  char* ws = (char*)d_ws;
  const size_t szXB = (size_t)MROWS * DMODEL * 2;
  const size_t szW  = (size_t)DMODEL * DFF * 2;
  u16* xb   = (u16*)(ws);
  u16* wgT  = (u16*)(ws + szXB);
  u16* wuT  = (u16*)(ws + szXB + szW);
  u16* wdT  = (u16*)(ws + szXB + 2 * szW);
  u16* gate = (u16*)(ws + szXB + 3 * szW);  // [M][DFF] bf16; becomes h in place

  k_cvt_x<<<(MROWS * DMODEL) / 1024, 256, 0, stream>>>(x, xb);
  k_dequant_T<<<dim3(DFF / 32, DMODEL / 32), 256, 0, stream>>>(qg, zg, sg, wgT, DMODEL, DFF);
  k_dequant_T<<<dim3(DFF / 32, DMODEL / 32), 256, 0, stream>>>(qu, zu, su, wuT, DMODEL, DFF);
  k_dequant_T<<<dim3(DMODEL / 32, DFF / 32), 256, 0, stream>>>(qd, zd, sd, wdT, DFF, DMODEL);

  k_gemm<0><<<(MROWS / 128) * (DFF / 128), 256, 0, stream>>>(xb, wgT, gate, MROWS, DFF, DMODEL);
  k_gemm<1><<<(MROWS / 128) * (DFF / 128), 256, 0, stream>>>(xb, wuT, gate, MROWS, DFF, DMODEL);
  k_gemm<2><<<(MROWS / 128) * (DMODEL / 128), 256, 0, stream>>>(gate, wdT, out, MROWS, DMODEL, DFF);
}

// Round 3
// 2687.849 us; speedup vs baseline: 5.3179x; 1.0921x over previous
//
#include <hip/hip_runtime.h>
#include <cstdint>

typedef unsigned short u16;
typedef unsigned int u32;
typedef __bf16 bf16_t;
typedef bf16_t bf16x8 __attribute__((ext_vector_type(8)));
typedef float f32x4 __attribute__((ext_vector_type(4)));

#define DMODEL 4096
#define DFF 11008
#define MROWS 8192

__device__ __forceinline__ u16 f2bf(float f) {
  u32 u = __builtin_bit_cast(u32, f);
  u += 0x7FFFu + ((u >> 16) & 1u);   // RNE
  return (u16)(u >> 16);
}
__device__ __forceinline__ float bf2f(u16 h) {
  return __builtin_bit_cast(float, (u32)h << 16);
}

// async global->LDS, 16B per lane, wave-uniform LDS base + lane*16
#define GLD16(gptr, lptr)                                                  \
  __builtin_amdgcn_global_load_lds(                                        \
      (const __attribute__((address_space(1))) u32*)(gptr),                \
      (__attribute__((address_space(3))) u32*)(lptr), 16, 0, 0)

// ---------------- x -> bf16 ----------------
__global__ void k_cvt_x(const float* __restrict__ x, u16* __restrict__ xb) {
  size_t i = (size_t)blockIdx.x * blockDim.x + threadIdx.x;
  float4 v = reinterpret_cast<const float4*>(x)[i];
  ushort4 o;
  o.x = f2bf(v.x); o.y = f2bf(v.y); o.z = f2bf(v.z); o.w = f2bf(v.w);
  reinterpret_cast<ushort4*>(xb)[i] = o;
}

// ------- dequant (q - z) * s, write TRANSPOSED wT[N][K] as bf16 -------
__global__ void k_dequant_T(const int* __restrict__ q, const int* __restrict__ z,
                            const float* __restrict__ s, u16* __restrict__ wT,
                            int K, int N) {
  __shared__ u16 tile[32][33];
  const int tx = threadIdx.x & 31, ty = threadIdx.x >> 5;
  const int n0 = blockIdx.x << 5, k0 = blockIdx.y << 5;
#pragma unroll
  for (int i = 0; i < 4; ++i) {
    int r = ty + i * 8;
    int k = k0 + r;
    int g = k >> 7;
    size_t zoff = (size_t)g * N + n0 + tx;
    float val = (float)(q[(size_t)k * N + n0 + tx] - z[zoff]) * s[zoff];
    tile[r][tx] = f2bf(val);
  }
  __syncthreads();
#pragma unroll
  for (int i = 0; i < 4; ++i) {
    int r = ty + i * 8;
    wT[(size_t)(n0 + r) * K + k0 + tx] = tile[tx][r];
  }
}

// ======== 256x256 8-phase GEMM: C[M,N] = A[M,K] * BT[N,K]^T ========
// 512 thr = 8 waves (2M x 4N), BK=64 split in 2 K-halves, dbuf LDS 128KB.
// Phase p of 8 per iter (2 K-tiles/iter). Stage 1 operand-half per phase,
// consumed 5-6 phases later; vmcnt(4) checkpoints at phases 4 and 8 only.
// Raw s_barrier (no vmcnt drain). Swizzle: LDS[row][s] = G[row][s^((row>>1)&3)].
template <int EPI>
__global__ __launch_bounds__(512, 2) void k_gemm8(
    const u16* __restrict__ A, const u16* __restrict__ BT,
    void* C, int Mdim, int Ndim, int Kdim) {
  __shared__ u16 As[2][2][256 * 32];  // [buf][khalf][row*32+col]
  __shared__ u16 Bs[2][2][256 * 32];

  const int nbn = Ndim >> 8;
  int bid = blockIdx.x;
  { const int cpx = gridDim.x >> 3; bid = (bid & 7) * cpx + (bid >> 3); }
  const int m0 = (bid / nbn) << 8;
  const int n0 = (bid % nbn) << 8;
  const int t = threadIdx.x;
  const int lane = t & 63;
  const int wid = t >> 6;
  const int wr = wid >> 2, wc = wid & 3;   // 2M x 4N waves; 128x64 out each
  const int r16 = lane & 15, quad = lane >> 4;

  // ---- staging (global -> LDS direct). One half = 256 rows x 32 cols x 2B
  // = 16KB = 2 GLD16/thread. Lane l -> lds row wid*16 + l/4, slot l&3.
  // Source column-slot pre-swizzled: (l&3) ^ ((l>>3)&3)  [= slot^((row>>1)&3)].
  const int lrow4 = lane >> 2;
  const int sslot = ((lane & 3) ^ ((lane >> 3) & 3)) << 3;  // u16 units
  const u16* Asrc = A + (size_t)(m0 + wid * 16 + lrow4) * Kdim + sslot;
  const u16* Bsrc = BT + (size_t)(n0 + wid * 16 + lrow4) * Kdim + sslot;
  const size_t rstep = (size_t)128 * Kdim;
  const int lb = wid * 512;  // wave chunk base (u16) within a [256][32] region
  const int ntiles = Kdim >> 6;

#define SA(tt, kh, bf) do {                                                \
    int ttw = (tt) < ntiles ? (tt) : (tt) - ntiles;  /* tail wrap */       \
    size_t ko = ((size_t)ttw << 6) + ((kh) << 5);                          \
    GLD16(Asrc + ko,         &As[bf][kh][lb]);                             \
    GLD16(Asrc + ko + rstep, &As[bf][kh][lb + 4096]);                      \
  } while (0)
#define SB(tt, kh, bf) do {                                                \
    int ttw = (tt) < ntiles ? (tt) : (tt) - ntiles;                        \
    size_t ko = ((size_t)ttw << 6) + ((kh) << 5);                          \
    GLD16(Bsrc + ko,         &Bs[bf][kh][lb]);                             \
    GLD16(Bsrc + ko + rstep, &Bs[bf][kh][lb + 4096]);                      \
  } while (0)

  // ---- fragment read offsets (swizzled): slot = quad ^ ((r16>>1)&3)
  const int fragoff = (quad ^ ((r16 >> 1) & 3)) << 3;  // u16 units
  const int abase = (wr * 128 + r16) * 32 + fragoff;
  const int bbase = (wc * 64 + r16) * 32 + fragoff;

  f32x4 acc[8][4];
  const f32x4 zf = {0.f, 0.f, 0.f, 0.f};
#pragma unroll
  for (int mf = 0; mf < 8; ++mf)
#pragma unroll
    for (int nf = 0; nf < 4; ++nf) acc[mf][nf] = zf;

#define BAR asm volatile("s_barrier" ::: "memory")
#define VM4 asm volatile("s_waitcnt vmcnt(4)" ::: "memory")

#define PHASE(bf, kk, mh, STG, VMW) do {                                   \
    bf16x8 av[4], bv[4];                                                   \
    _Pragma("unroll") for (int ii = 0; ii < 4; ++ii)                       \
      av[ii] = *reinterpret_cast<const bf16x8*>(                           \
          &As[bf][kk][abase + (mh) * 2048 + ii * 512]);                    \
    _Pragma("unroll") for (int nn = 0; nn < 4; ++nn)                       \
      bv[nn] = *reinterpret_cast<const bf16x8*>(                           \
          &Bs[bf][kk][bbase + nn * 512]);                                  \
    STG;                                                                   \
    BAR;                                                                   \
    __builtin_amdgcn_s_setprio(1);                                         \
    _Pragma("unroll") for (int ii = 0; ii < 4; ++ii)                       \
      _Pragma("unroll") for (int nn = 0; nn < 4; ++nn)                     \
        acc[(mh) * 4 + ii][nn] = __builtin_amdgcn_mfma_f32_16x16x32_bf16(  \
            av[ii], bv[nn], acc[(mh) * 4 + ii][nn], 0, 0, 0);              \
    __builtin_amdgcn_s_setprio(0);                                         \
    VMW;                                                                   \
    BAR;                                                                   \
  } while (0)

  // ---- prologue: t0 fully + t1-kh0; leave t1-kh0 (4 loads) in flight
  SA(0, 0, 0); SB(0, 0, 0); SA(0, 1, 0); SB(0, 1, 0); SA(1, 0, 1); SB(1, 0, 1);
  VM4;
  BAR;

  // ---- main loop: iter computes tiles 2i (buf0) then 2i+1 (buf1)
  const int NI = ntiles >> 1;
  for (int it = 0; it < NI; ++it) {
    const int t0 = it * 2;
    PHASE(0, 0, 0, SA(t0 + 1, 1, 1), (void)0);
    PHASE(0, 0, 1, SB(t0 + 1, 1, 1), (void)0);
    PHASE(0, 1, 0, SA(t0 + 2, 0, 0), (void)0);
    PHASE(0, 1, 1, SB(t0 + 2, 0, 0), VM4);
    PHASE(1, 0, 0, SA(t0 + 2, 1, 0), (void)0);
    PHASE(1, 0, 1, SB(t0 + 2, 1, 0), (void)0);
    PHASE(1, 1, 0, SA(t0 + 3, 0, 1), (void)0);
    PHASE(1, 1, 1, SB(t0 + 3, 0, 1), VM4);
  }
  asm volatile("s_waitcnt vmcnt(0)" ::: "memory");  // drain before epilogue

  // ---- epilogue. C/D layout: col = lane&15, row = quad*4 + j (m89-verified)
  const int rb0 = m0 + wr * 128 + quad * 4;
  const int cb0 = n0 + wc * 64 + r16;
#pragma unroll
  for (int mf = 0; mf < 8; ++mf) {
#pragma unroll
    for (int nf = 0; nf < 4; ++nf) {
      f32x4 v = acc[mf][nf];
      int row = rb0 + mf * 16;
      int col = cb0 + nf * 16;
#pragma unroll
      for (int j = 0; j < 4; ++j) {
        size_t idx = (size_t)(row + j) * Ndim + col;
        if constexpr (EPI == 0) {
          ((u16*)C)[idx] = f2bf(v[j]);
        } else if constexpr (EPI == 1) {
          u16* Cp = (u16*)C;
          float g = bf2f(Cp[idx]);
          float sv = g / (1.f + __expf(-g));
          Cp[idx] = f2bf(sv * v[j]);
        } else {
          ((float*)C)[idx] = v[j];
        }
      }
    }
  }
#undef SA
#undef SB
#undef PHASE
#undef BAR
#undef VM4
}

extern "C" void kernel_launch(void* const* d_in, const int* in_sizes, int n_in,
                              void* d_out, int out_size, void* d_ws, size_t ws_size,
                              hipStream_t stream) {
  const float* x  = (const float*)d_in[0];
  const int*   qg = (const int*)d_in[1];
  const int*   zg = (const int*)d_in[2];
  const float* sg = (const float*)d_in[3];
  const int*   qu = (const int*)d_in[4];
  const int*   zu = (const int*)d_in[5];
  const float* su = (const float*)d_in[6];
  const int*   qd = (const int*)d_in[7];
  const int*   zd = (const int*)d_in[8];
  const float* sd = (const float*)d_in[9];
  float* out = (float*)d_out;

  char* ws = (char*)d_ws;
  const size_t szXB = (size_t)MROWS * DMODEL * 2;
  const size_t szW  = (size_t)DMODEL * DFF * 2;
  u16* xb   = (u16*)(ws);
  u16* wgT  = (u16*)(ws + szXB);
  u16* wuT  = (u16*)(ws + szXB + szW);
  u16* wdT  = (u16*)(ws + szXB + 2 * szW);
  u16* gate = (u16*)(ws + szXB + 3 * szW);  // [M][DFF] bf16; becomes h in place

  k_cvt_x<<<(MROWS * DMODEL) / 1024, 256, 0, stream>>>(x, xb);
  k_dequant_T<<<dim3(DFF / 32, DMODEL / 32), 256, 0, stream>>>(qg, zg, sg, wgT, DMODEL, DFF);
  k_dequant_T<<<dim3(DFF / 32, DMODEL / 32), 256, 0, stream>>>(qu, zu, su, wuT, DMODEL, DFF);
  k_dequant_T<<<dim3(DMODEL / 32, DFF / 32), 256, 0, stream>>>(qd, zd, sd, wdT, DFF, DMODEL);

  k_gemm8<0><<<(MROWS / 256) * (DFF / 256), 512, 0, stream>>>(xb, wgT, gate, MROWS, DFF, DMODEL);
  k_gemm8<1><<<(MROWS / 256) * (DFF / 256), 512, 0, stream>>>(xb, wuT, gate, MROWS, DFF, DMODEL);
  k_gemm8<2><<<(MROWS / 256) * (DMODEL / 256), 512, 0, stream>>>(gate, wdT, out, MROWS, DMODEL, DFF);
}